// Round 8
// baseline (83.056 us; speedup 1.0000x reference)
//
#include <hip/hip_runtime.h>

typedef float f32x4 __attribute__((ext_vector_type(4)));
typedef short s16x8 __attribute__((ext_vector_type(8)));
typedef unsigned int u32;

__device__ __forceinline__ u32 f2bf(float x) {
    u32 u = __float_as_uint(x);
    return (u + 0x7FFFu + ((u >> 16) & 1u)) >> 16;
}
__device__ __forceinline__ u32 pk(float a, float b) {
    return f2bf(a) | (f2bf(b) << 16);
}
__device__ __forceinline__ int bh(int rowid) {            // bounce granule hash
    return (rowid ^ (rowid >> 4)) & 15;
}
__device__ __forceinline__ int g2(int uu) {               // W-plane 2-bit hash
    return (uu ^ (uu >> 2)) & 3;
}

#define A_PLANE 520        // shorts: [8 b][64 t] + 8 pad
#define A_SLOT  4160       // shorts: 8 px planes
#define SF_BASE 8320       // shorts; f32 bounce: 2 slots x 4096 f32

// 3 WG/CU deep-MLP version: W in regs (t-half staged), 8 b-chunks of 8,
// 1 barrier/chunk, store decoupled past the barrier, loads 2 chunks ahead.
__global__ __launch_bounds__(512, 6)
void upsample_mfma_kernel(const float* __restrict__ yt,
                          const float* __restrict__ Ht,
                          const float* __restrict__ biases,
                          float* __restrict__ out)
{
    __shared__ __align__(16) unsigned short S[24704];   // 49408 B

    const int wg  = blockIdx.x;
    const int xcd = wg & 7, jj0 = wg >> 3;
    const int py  = xcd * 8 + (jj0 & 7);    // XCD k owns py in [8k, 8k+8)
    const int pxo = jj0 >> 3;
    const int px0 = pxo * 8;
    const int tid = (int)threadIdx.x;

    // ---- A staging coords: 2 lanes x f32x4 = 32B runs ----
    const int pxh = tid & 1;
    const int ab  = (tid >> 1) & 7;          // b within 8-chunk
    const int atq = tid >> 4;                // 0..31 -> t = atq*2 + {0,1}
    const float* a_base = yt + (size_t)ab * 262144 + (size_t)(atq * 2) * 4096
                        + py * 64 + px0 + pxh * 4;

    // chunk-0 loads first (land under W staging)
    f32x4 v0 = *(const f32x4*)(a_base);
    f32x4 v1 = *(const f32x4*)(a_base + 4096);

    // ---- W staging coords: 16 lanes x 16B = 256B runs ----
    const int c4 = tid & 15, w_uy = (tid >> 4) & 7, tq = tid >> 7;  // tq 0..3
    const float* wb = Ht + (size_t)(py * 8 + w_uy) * 512 + px0 * 8 + c4 * 4;

    // ---- compute coords ----
    const int wv = tid >> 6, l = tid & 63, r = l & 15, q = l >> 4;

    // ============ prologue: W in 2 t-halves -> registers ============
    s16x8 wf[4][2];
    #pragma unroll
    for (int h = 0; h < 2; ++h) {
        if (h) __syncthreads();              // half-0 extraction done
        f32x4 w8[8];
        #pragma unroll
        for (int k = 0; k < 8; ++k)
            w8[k] = *(const f32x4*)(wb + (size_t)(h * 32 + tq * 8 + k) * 262144);
        #pragma unroll
        for (int cc = 0; cc < 4; ++cc) {
            const int c = c4 * 4 + cc, pxl = c >> 3, uu = w_uy * 8 + (c & 7);
            uint4 g;
            g.x = pk(w8[0][cc], w8[1][cc]);
            g.y = pk(w8[2][cc], w8[3][cc]);
            g.z = pk(w8[4][cc], w8[5][cc]);
            g.w = pk(w8[6][cc], w8[7][cc]);
            *(uint4*)&S[pxl * 2048 + uu * 32 + ((tq ^ g2(uu) ^ pxl) & 3) * 8] = g;
        }
        __syncthreads();
        #pragma unroll
        for (int nb = 0; nb < 4; ++nb) {
            const int uu = nb * 16 + r;
            wf[nb][h] = *(const s16x8*)&S[wv * 2048 + uu * 32
                                          + ((q ^ g2(uu) ^ wv) & 3) * 8];
        }
    }

    const int p = py * 64 + px0 + wv;
    float bv4[4];
    #pragma unroll
    for (int nb = 0; nb < 4; ++nb)
        bv4[nb] = biases[(size_t)p * 64 + nb * 16 + r];

    __syncthreads();                         // W region now reusable

    // ---- A write / issue helpers ----
    auto writeA = [&](int slot) {
        const int col = (atq * 2) ^ (ab << 3);
        #pragma unroll
        for (int pp = 0; pp < 4; ++pp)
            *(u32*)&S[slot * A_SLOT + (pxh * 4 + pp) * A_PLANE + ab * 64 + col] =
                pk(v0[pp], v1[pp]);
    };
    auto issueA = [&](int chunk) {
        const float* ap = a_base + (size_t)chunk * 8 * 262144;
        v0 = *(const f32x4*)(ap);
        v1 = *(const f32x4*)(ap + 4096);
    };

    writeA(0);
    issueA(1);
    __syncthreads();

    float* Sf = (float*)&S[SF_BASE];

    // ============ main loop: 8 chunks of 8 b, 1 barrier each ============
    #pragma unroll
    for (int i = 0; i < 8; ++i) {
        // compute chunk i from A slot i&1
        f32x4 acc[4];
        #pragma unroll
        for (int nb = 0; nb < 4; ++nb)
            acc[nb] = (f32x4){bv4[nb], bv4[nb], bv4[nb], bv4[nb]};
        #pragma unroll
        for (int ks = 0; ks < 2; ++ks) {
            const int colA = (ks * 32 + q * 8) ^ ((r & 7) << 3);
            s16x8 af = *(const s16x8*)&S[(i & 1) * A_SLOT + wv * A_PLANE
                                         + (r & 7) * 64 + colA];
            #pragma unroll
            for (int nb = 0; nb < 4; ++nb)
                acc[nb] = __builtin_amdgcn_mfma_f32_16x16x32_bf16(
                    af, wf[nb][ks], acc[nb], 0, 0, 0);
        }

        if (i < 7) {
            writeA((i + 1) & 1);             // other slot: safe pre-barrier
            if (i < 6) issueA(i + 2);        // keep 2 chunks of loads in flight
        }

        // bounce acc -> Sf slot i&1 (rows bl<8 live in q<2 lanes)
        if (q < 2) {
            #pragma unroll
            for (int nb = 0; nb < 4; ++nb) {
                const int uyb = nb * 2 + (r >> 3);
                const int c4l = wv * 2 + ((r & 7) >> 2);
                const int e   = r & 3;
                #pragma unroll
                for (int ii = 0; ii < 4; ++ii) {
                    const int rowid = (q * 4 + ii) * 8 + uyb;
                    Sf[(i & 1) * 4096 + rowid * 64
                       + ((c4l ^ bh(rowid)) << 2) + e] = acc[nb][ii];
                }
            }
        }
        __syncthreads();

        // coalesced store (past the barrier: overlaps next chunk's front)
        #pragma unroll
        for (int jj = 0; jj < 2; ++jj) {
            const int slot = jj * 512 + tid;          // 1024 f32x4 slots
            const int bl = slot >> 7, rem = slot & 127;
            const int uy = rem >> 4, c4s = rem & 15;
            const int rowid = bl * 8 + uy;
            f32x4 vv = *(const f32x4*)&Sf[(i & 1) * 4096 + rowid * 64
                                          + ((c4s ^ bh(rowid)) << 2)];
            *(f32x4*)&out[((size_t)(i * 8 + bl) * 512 + py * 8 + uy) * 512
                          + px0 * 8 + c4s * 4] = vv;
        }
    }
}

extern "C" void kernel_launch(void* const* d_in, const int* in_sizes, int n_in,
                              void* d_out, int out_size, void* d_ws, size_t ws_size,
                              hipStream_t stream) {
    const float* yt     = (const float*)d_in[0];
    const float* Ht     = (const float*)d_in[1];
    const float* biases = (const float*)d_in[2];
    float* out          = (float*)d_out;
    upsample_mfma_kernel<<<dim3(512), dim3(512), 0, stream>>>(yt, Ht, biases, out);
}

// Round 9
// 39.109 us; speedup vs baseline: 2.1237x; 2.1237x over previous
//
#include <hip/hip_runtime.h>

typedef float f32x4 __attribute__((ext_vector_type(4)));
typedef short s16x8 __attribute__((ext_vector_type(8)));
typedef unsigned int u32;

__device__ __forceinline__ u32 f2bf(float x) {
    u32 u = __float_as_uint(x);
    return (u + 0x7FFFu + ((u >> 16) & 1u)) >> 16;
}
__device__ __forceinline__ u32 pk(float a, float b) {
    return f2bf(a) | (f2bf(b) << 16);
}
__device__ __forceinline__ int bh(int rowid) {            // bounce granule hash
    return (rowid ^ (rowid >> 4)) & 15;
}
__device__ __forceinline__ int g2(int uu) {               // W-plane 2-bit hash
    return (uu ^ (uu >> 2)) & 3;
}

#define A_PLANE 520        // shorts: [8 b][64 t] + 8 pad
#define A_SLOT  4160       // shorts: 8 px planes
#define SF_BASE 8320       // shorts; f32 bounce: 2 slots x 4096 f32

// r8 deep pipeline (8 b-chunks, 1 barrier/chunk, decoupled store) with the
// register spill fixed: launch_bounds(512,4). nt-stores keep inputs in L3.
__global__ __launch_bounds__(512, 4)
void upsample_mfma_kernel(const float* __restrict__ yt,
                          const float* __restrict__ Ht,
                          const float* __restrict__ biases,
                          float* __restrict__ out)
{
    __shared__ __align__(16) unsigned short S[24704];   // 49408 B

    const int wg  = blockIdx.x;
    const int xcd = wg & 7, jj0 = wg >> 3;
    const int py  = xcd * 8 + (jj0 & 7);    // XCD k owns py in [8k, 8k+8)
    const int pxo = jj0 >> 3;
    const int px0 = pxo * 8;
    const int tid = (int)threadIdx.x;

    // ---- A staging coords: 2 lanes x f32x4 = 32B runs ----
    const int pxh = tid & 1;
    const int ab  = (tid >> 1) & 7;          // b within 8-chunk
    const int atq = tid >> 4;                // 0..31 -> t = atq*2 + {0,1}
    const float* a_base = yt + (size_t)ab * 262144 + (size_t)(atq * 2) * 4096
                        + py * 64 + px0 + pxh * 4;

    // chunk-0 loads first (land under W staging)
    f32x4 v0 = *(const f32x4*)(a_base);
    f32x4 v1 = *(const f32x4*)(a_base + 4096);

    // ---- W staging coords: 16 lanes x 16B = 256B runs ----
    const int c4 = tid & 15, w_uy = (tid >> 4) & 7, tq = tid >> 7;  // tq 0..3
    const float* wb = Ht + (size_t)(py * 8 + w_uy) * 512 + px0 * 8 + c4 * 4;

    // ---- compute coords ----
    const int wv = tid >> 6, l = tid & 63, r = l & 15, q = l >> 4;

    // ============ prologue: W in 2 t-halves -> registers ============
    s16x8 wf[4][2];
    #pragma unroll
    for (int h = 0; h < 2; ++h) {
        if (h) __syncthreads();              // half-0 extraction done
        f32x4 w8[8];
        #pragma unroll
        for (int k = 0; k < 8; ++k)
            w8[k] = *(const f32x4*)(wb + (size_t)(h * 32 + tq * 8 + k) * 262144);
        #pragma unroll
        for (int cc = 0; cc < 4; ++cc) {
            const int c = c4 * 4 + cc, pxl = c >> 3, uu = w_uy * 8 + (c & 7);
            uint4 g;
            g.x = pk(w8[0][cc], w8[1][cc]);
            g.y = pk(w8[2][cc], w8[3][cc]);
            g.z = pk(w8[4][cc], w8[5][cc]);
            g.w = pk(w8[6][cc], w8[7][cc]);
            *(uint4*)&S[pxl * 2048 + uu * 32 + ((tq ^ g2(uu) ^ pxl) & 3) * 8] = g;
        }
        __syncthreads();
        #pragma unroll
        for (int nb = 0; nb < 4; ++nb) {
            const int uu = nb * 16 + r;
            wf[nb][h] = *(const s16x8*)&S[wv * 2048 + uu * 32
                                          + ((q ^ g2(uu) ^ wv) & 3) * 8];
        }
    }

    const int p = py * 64 + px0 + wv;
    float bv4[4];
    #pragma unroll
    for (int nb = 0; nb < 4; ++nb)
        bv4[nb] = biases[(size_t)p * 64 + nb * 16 + r];

    __syncthreads();                         // W region now reusable

    // ---- A write / issue helpers ----
    auto writeA = [&](int slot) {
        const int col = (atq * 2) ^ (ab << 3);
        #pragma unroll
        for (int pp = 0; pp < 4; ++pp)
            *(u32*)&S[slot * A_SLOT + (pxh * 4 + pp) * A_PLANE + ab * 64 + col] =
                pk(v0[pp], v1[pp]);
    };
    auto issueA = [&](int chunk) {
        const float* ap = a_base + (size_t)chunk * 8 * 262144;
        v0 = *(const f32x4*)(ap);
        v1 = *(const f32x4*)(ap + 4096);
    };

    writeA(0);
    issueA(1);
    __syncthreads();

    float* Sf = (float*)&S[SF_BASE];

    // ============ main loop: 8 chunks of 8 b, 1 barrier each ============
    #pragma unroll
    for (int i = 0; i < 8; ++i) {
        // compute chunk i from A slot i&1
        f32x4 acc[4];
        #pragma unroll
        for (int nb = 0; nb < 4; ++nb)
            acc[nb] = (f32x4){bv4[nb], bv4[nb], bv4[nb], bv4[nb]};
        #pragma unroll
        for (int ks = 0; ks < 2; ++ks) {
            const int colA = (ks * 32 + q * 8) ^ ((r & 7) << 3);
            s16x8 af = *(const s16x8*)&S[(i & 1) * A_SLOT + wv * A_PLANE
                                         + (r & 7) * 64 + colA];
            #pragma unroll
            for (int nb = 0; nb < 4; ++nb)
                acc[nb] = __builtin_amdgcn_mfma_f32_16x16x32_bf16(
                    af, wf[nb][ks], acc[nb], 0, 0, 0);
        }

        if (i < 7) {
            writeA((i + 1) & 1);             // other slot: safe pre-barrier
            if (i < 6) issueA(i + 2);        // keep 2 chunks of loads in flight
        }

        // bounce acc -> Sf slot i&1 (rows bl<8 live in q<2 lanes)
        if (q < 2) {
            #pragma unroll
            for (int nb = 0; nb < 4; ++nb) {
                const int uyb = nb * 2 + (r >> 3);
                const int c4l = wv * 2 + ((r & 7) >> 2);
                const int e   = r & 3;
                #pragma unroll
                for (int ii = 0; ii < 4; ++ii) {
                    const int rowid = (q * 4 + ii) * 8 + uyb;
                    Sf[(i & 1) * 4096 + rowid * 64
                       + ((c4l ^ bh(rowid)) << 2) + e] = acc[nb][ii];
                }
            }
        }
        __syncthreads();

        // coalesced nt-store (past the barrier: overlaps next chunk's front)
        #pragma unroll
        for (int jj = 0; jj < 2; ++jj) {
            const int slot = jj * 512 + tid;          // 1024 f32x4 slots
            const int bl = slot >> 7, rem = slot & 127;
            const int uy = rem >> 4, c4s = rem & 15;
            const int rowid = bl * 8 + uy;
            f32x4 vv = *(const f32x4*)&Sf[(i & 1) * 4096 + rowid * 64
                                          + ((c4s ^ bh(rowid)) << 2)];
            __builtin_nontemporal_store(vv,
                (f32x4*)&out[((size_t)(i * 8 + bl) * 512 + py * 8 + uy) * 512
                             + px0 * 8 + c4s * 4]);
        }
    }
}

extern "C" void kernel_launch(void* const* d_in, const int* in_sizes, int n_in,
                              void* d_out, int out_size, void* d_ws, size_t ws_size,
                              hipStream_t stream) {
    const float* yt     = (const float*)d_in[0];
    const float* Ht     = (const float*)d_in[1];
    const float* biases = (const float*)d_in[2];
    float* out          = (float*)d_out;
    upsample_mfma_kernel<<<dim3(512), dim3(512), 0, stream>>>(yt, Ht, biases, out);
}

// Round 10
// 36.875 us; speedup vs baseline: 2.2524x; 1.0606x over previous
//
#include <hip/hip_runtime.h>

typedef float f32x4 __attribute__((ext_vector_type(4)));
typedef short s16x8 __attribute__((ext_vector_type(8)));
typedef unsigned int u32;

__device__ __forceinline__ u32 f2bf(float x) {
    u32 u = __float_as_uint(x);
    return (u + 0x7FFFu + ((u >> 16) & 1u)) >> 16;
}
__device__ __forceinline__ u32 pk(float a, float b) {
    return f2bf(a) | (f2bf(b) << 16);
}
// W planes: [64 rows][64 t] bf16, XOR on 16B granules
__device__ __forceinline__ int swz(int row, int t) {
    int g = ((row ^ (row >> 3)) & 7) << 3;
    return row * 64 + (t ^ g);
}
// A planes: [16 rows][64 t] bf16
__device__ __forceinline__ int swzA(int row, int t) {
    return row * 64 + (t ^ ((row & 7) << 3));
}
// bounce granule hash ([128 rows][64 f32])
__device__ __forceinline__ int bh(int rowid) {
    return (rowid ^ (rowid >> 4)) & 15;
}

#define A_PLANE 1032          // shorts per A px-plane ([16][64] + 8 pad)
#define A_SLOT  (8 * A_PLANE) // 8256 shorts = 16512 B
#define BOUNCE  (2 * A_SLOT)  // short offset 16512 -> byte 33024 (16B aligned)

// Best-known kernel (round 7, 36.6us): W-in-registers, py-contiguous XCD map,
// 4-chunk b-pipeline interleaving reads/compute/stores, early-issued yt loads,
// LDS-bounced coalesced epilogue.
__global__ __launch_bounds__(512, 4)
void upsample_mfma_kernel(const float* __restrict__ yt,
                          const float* __restrict__ Ht,
                          const float* __restrict__ biases,
                          float* __restrict__ out)
{
    __shared__ __align__(16) unsigned short S[32896];   // 65792 B

    const int wg  = blockIdx.x;
    const int xcd = wg & 7;
    const int j   = wg >> 3;
    const int py  = xcd * 8 + (j & 7);   // XCD k owns py in [8k, 8k+8)
    const int pxo = j >> 3;
    const int px0 = pxo * 8;
    const int tid = (int)threadIdx.x;

    // ---- A staging coords: 8px*4B = 32B runs, 2 lanes each ----
    const int pxh = tid & 1;
    const int ab  = (tid >> 1) & 15;     // b within 16-chunk
    const int atq = tid >> 5;            // 0..15, t = atq*4 + k
    const float* a_base = yt + (size_t)ab * 262144 + (size_t)atq * 4 * 4096
                        + py * 64 + px0 + pxh * 4;

    f32x4 v[4];
    // issue chunk-0 yt loads FIRST (land during Ht staging)
    #pragma unroll
    for (int k = 0; k < 4; ++k)
        v[k] = *(const f32x4*)(a_base + (size_t)k * 4096);

    // ============ Phase 1: stage W (Ht slice) -> LDS ============
    {
        const int c4 = tid & 15, uy = (tid >> 4) & 7, tq = tid >> 7;
        const float* wb = Ht + (size_t)(py * 8 + uy) * 512 + px0 * 8 + c4 * 4;
        #pragma unroll
        for (int ph = 0; ph < 2; ++ph) {
            const int t0 = ph * 32 + tq * 8;
            f32x4 w8[8];
            #pragma unroll
            for (int k = 0; k < 8; ++k)
                w8[k] = *(const f32x4*)(wb + (size_t)(t0 + k) * 262144);
            #pragma unroll
            for (int cc = 0; cc < 4; ++cc) {
                const int c = c4 * 4 + cc, pxl = c >> 3, uu = uy * 8 + (c & 7);
                uint4 g;
                g.x = pk(w8[0][cc], w8[1][cc]);
                g.y = pk(w8[2][cc], w8[3][cc]);
                g.z = pk(w8[4][cc], w8[5][cc]);
                g.w = pk(w8[6][cc], w8[7][cc]);
                *(uint4*)&S[pxl * 4096 + swz(uu, t0)] = g;
            }
        }
    }
    __syncthreads();

    // ============ Phase 2: W frags -> regs, bias ============
    const int wv = tid >> 6, l = tid & 63, r = l & 15, q = l >> 4;
    s16x8 wf[4][2];
    #pragma unroll
    for (int nb = 0; nb < 4; ++nb)
        #pragma unroll
        for (int ks = 0; ks < 2; ++ks)
            wf[nb][ks] = *(const s16x8*)&S[wv * 4096 + swz(nb * 16 + r, ks * 32 + q * 8)];
    const int px = px0 + wv, p = py * 64 + px;
    float bv[4];
    #pragma unroll
    for (int nb = 0; nb < 4; ++nb)
        bv[nb] = biases[(size_t)p * 64 + nb * 16 + r];
    __syncthreads();   // W reads done -> LDS reusable

    // ---- helpers ----
    auto writeA = [&](int slot) {
        #pragma unroll
        for (int pp = 0; pp < 4; ++pp) {
            const int pxl = pxh * 4 + pp;
            *(uint2*)&S[slot * A_SLOT + pxl * A_PLANE + swzA(ab, atq * 4)] =
                make_uint2(pk(v[0][pp], v[1][pp]), pk(v[2][pp], v[3][pp]));
        }
    };
    auto issueA = [&](int chunk) {
        const float* ap = a_base + (size_t)chunk * 16 * 262144;
        #pragma unroll
        for (int k = 0; k < 4; ++k)
            v[k] = *(const f32x4*)(ap + (size_t)k * 4096);
    };

    writeA(0);
    issueA(1);
    __syncthreads();

    float* Sf = (float*)&S[BOUNCE];

    // ============ pipelined main loop over 4 b-chunks ============
    #pragma unroll
    for (int i = 0; i < 4; ++i) {
        // compute chunk i (wave-local A plane)
        f32x4 acc[4];
        #pragma unroll
        for (int nb = 0; nb < 4; ++nb)
            acc[nb] = (f32x4){bv[nb], bv[nb], bv[nb], bv[nb]};
        #pragma unroll
        for (int ks = 0; ks < 2; ++ks) {
            s16x8 af = *(const s16x8*)&S[(i & 1) * A_SLOT + wv * A_PLANE
                                         + swzA(r, ks * 32 + q * 8)];
            #pragma unroll
            for (int nb = 0; nb < 4; ++nb)
                acc[nb] = __builtin_amdgcn_mfma_f32_16x16x32_bf16(
                    af, wf[nb][ks], acc[nb], 0, 0, 0);
        }

        if (i < 3) {
            writeA((i + 1) & 1);   // slot last read at compute(i-1): safe
            if (i < 2) issueA(i + 2);
        }

        // bounce acc -> Sf ([rowid = bl*8+uy][64 cols], XOR-hashed granules)
        #pragma unroll
        for (int nb = 0; nb < 4; ++nb) {
            const int uy  = nb * 2 + (r >> 3);
            const int c4l = wv * 2 + ((r & 7) >> 2);
            const int e   = r & 3;
            #pragma unroll
            for (int ii = 0; ii < 4; ++ii) {
                const int bl    = q * 4 + ii;
                const int rowid = bl * 8 + uy;
                Sf[rowid * 64 + ((c4l ^ bh(rowid)) << 2) + e] = acc[nb][ii];
            }
        }
        __syncthreads();

        // coalesced store: 2048 f32x4 slots, 4 per thread
        #pragma unroll
        for (int jj = 0; jj < 4; ++jj) {
            const int slot = jj * 512 + tid;
            const int bl = slot >> 7, rem = slot & 127;
            const int uy = rem >> 4, c4 = rem & 15;
            const int rowid = bl * 8 + uy;
            f32x4 vv = *(const f32x4*)&Sf[rowid * 64 + ((c4 ^ bh(rowid)) << 2)];
            *(f32x4*)&out[((size_t)(i * 16 + bl) * 512 + py * 8 + uy) * 512
                          + px0 * 8 + c4 * 4] = vv;
        }
        __syncthreads();
    }
}

extern "C" void kernel_launch(void* const* d_in, const int* in_sizes, int n_in,
                              void* d_out, int out_size, void* d_ws, size_t ws_size,
                              hipStream_t stream) {
    const float* yt     = (const float*)d_in[0];
    const float* Ht     = (const float*)d_in[1];
    const float* biases = (const float*)d_in[2];
    float* out          = (float*)d_out;
    upsample_mfma_kernel<<<dim3(512), dim3(512), 0, stream>>>(yt, Ht, biases, out);
}